// Round 2
// baseline (480.734 us; speedup 1.0000x reference)
//
#include <hip/hip_runtime.h>
#include <hip/hip_bf16.h>

// SeRNN forward: 6 channel-wise LSTMs (H=32) over T=256, B=1024, then MLP head.
// Outputs (concat): out [B,2] (2048 floats) then x7 [B,T,192].

#define Bv 1024
#define Tv 256
#define Cv 6
#define Hv 32
#define Gv 128   // 4*H, PyTorch gate order i,f,g,o

__device__ __forceinline__ float fsig(float x) {
    // sigmoid via v_exp_f32 + v_rcp_f32 (~1 ULP each)
    return __builtin_amdgcn_rcpf(1.0f + __expf(-x));
}
__device__ __forceinline__ float ftanh(float x) {
    float ax = fabsf(x);
    float e  = __expf(-2.0f * ax);
    float r  = (1.0f - e) * __builtin_amdgcn_rcpf(1.0f + e);
    return copysignf(r, x);
}

// One wave per (b,c) sequence. Lane l owns gate rows l and l+64 (64 weight VGPRs).
// h state broadcast through a per-wave LDS buffer (same-address float4 reads).
__global__ __launch_bounds__(256) void lstm_kernel(
    const float* __restrict__ x,      // [B,T,C]
    const float* __restrict__ w_ih,   // [C,G]
    const float* __restrict__ w_hh,   // [C,G,H]
    const float* __restrict__ b_ih,   // [C,G]
    const float* __restrict__ b_hh,   // [C,G]
    float* __restrict__ x7)           // [B,T,C*H]
{
    __shared__ float hbuf[4][Hv];

    const int wave = threadIdx.x >> 6;
    const int lane = threadIdx.x & 63;
    const int c    = blockIdx.x % Cv;            // block-uniform channel
    const int b    = (blockIdx.x / Cv) * 4 + wave;

    // ---- load recurrent weights into registers: rows (lane) and (lane+64) ----
    float w0[Hv], w1r[Hv];
    const float* whc = w_hh + (size_t)c * (Gv * Hv);
    #pragma unroll
    for (int j4 = 0; j4 < Hv / 4; ++j4) {
        float4 a = *(const float4*)(whc + lane * Hv + j4 * 4);
        float4 q = *(const float4*)(whc + (lane + 64) * Hv + j4 * 4);
        w0[j4*4+0] = a.x; w0[j4*4+1] = a.y; w0[j4*4+2] = a.z; w0[j4*4+3] = a.w;
        w1r[j4*4+0] = q.x; w1r[j4*4+1] = q.y; w1r[j4*4+2] = q.z; w1r[j4*4+3] = q.w;
    }
    const float wi0 = w_ih[c * Gv + lane];
    const float wi1 = w_ih[c * Gv + lane + 64];
    const float bb0 = b_ih[c * Gv + lane] + b_hh[c * Gv + lane];
    const float bb1 = b_ih[c * Gv + lane + 64] + b_hh[c * Gv + lane + 64];

    if (lane < Hv) hbuf[wave][lane] = 0.0f;   // h0 = 0 (same-wave ordering via lgkmcnt)
    float cc = 0.0f;                          // cell state for unit (lane&31), both halves

    const float* xp = x + (size_t)b * Tv * Cv + c;
    float* op = x7 + (size_t)b * Tv * (Cv * Hv) + c * Hv + (lane & 31);

    float xt = xp[0];
    for (int t = 0; t < Tv; ++t) {
        // software-pipeline next x_t (uniform-address scalar load)
        float xn = (t + 1 < Tv) ? xp[(size_t)(t + 1) * Cv] : 0.0f;

        // gates: two accumulator chains per gate for dep-latency cover
        float g0a = bb0 + xt * wi0, g0b = 0.0f;
        float g1a = bb1 + xt * wi1, g1b = 0.0f;
        const float4* hb4 = (const float4*)hbuf[wave];
        #pragma unroll
        for (int j4 = 0; j4 < Hv / 4; ++j4) {
            float4 h4 = hb4[j4];               // broadcast ds_read_b128
            g0a += w0[j4*4+0] * h4.x;  g1a += w1r[j4*4+0] * h4.x;
            g0b += w0[j4*4+1] * h4.y;  g1b += w1r[j4*4+1] * h4.y;
            g0a += w0[j4*4+2] * h4.z;  g1a += w1r[j4*4+2] * h4.z;
            g0b += w0[j4*4+3] * h4.w;  g1b += w1r[j4*4+3] * h4.w;
        }
        float g0 = g0a + g0b;   // lanes<32: i-gate,  lanes>=32: f-gate
        float g1 = g1a + g1b;   // lanes<32: g-gate,  lanes>=32: o-gate

        // wave-uniform activations (no divergent branches), then half-exchange
        float s0 = fsig(g0);    // sigmoid(i) | sigmoid(f)
        float s1 = fsig(g1);    //   (unused) | sigmoid(o)
        float t1 = ftanh(g1);   //   tanh(g)  | (unused)
        float s0x = __shfl_xor(s0, 32);
        float s1x = __shfl_xor(s1, 32);
        float t1x = __shfl_xor(t1, 32);
        bool lo = (lane < 32);
        float i_s = lo ? s0  : s0x;
        float f_s = lo ? s0x : s0;
        float o_s = lo ? s1x : s1;
        float g_t = lo ? t1  : t1x;

        cc = f_s * cc + i_s * g_t;            // replicated in both halves
        float hn = o_s * ftanh(cc);

        if (lane < Hv) {
            hbuf[wave][lane] = hn;            // next step's broadcast source
            op[(size_t)t * (Cv * Hv)] = hn;   // x7[b,t,c*32+lane]
        }
        xt = xn;
    }
}

// MLP head on x7[:, T-1, :]: fc1(192->64)+relu, fc3(64->64)+relu, fc2(64->2)
__global__ __launch_bounds__(64) void head_kernel(
    const float* __restrict__ x7,
    const float* __restrict__ w1, const float* __restrict__ b1,
    const float* __restrict__ w3, const float* __restrict__ b3,
    const float* __restrict__ w2, const float* __restrict__ b2,
    float* __restrict__ out)
{
    const int b   = blockIdx.x;
    const int tid = threadIdx.x;
    __shared__ float xr[Cv * Hv];
    __shared__ float h1[64];
    __shared__ float h2[64];

    const float* xrow = x7 + (size_t)b * Tv * (Cv * Hv) + (size_t)(Tv - 1) * (Cv * Hv);
    for (int k = tid; k < Cv * Hv; k += 64) xr[k] = xrow[k];
    __syncthreads();

    float a1 = b1[tid];
    const float* w1r = w1 + tid * (Cv * Hv);
    #pragma unroll 4
    for (int k = 0; k < Cv * Hv; ++k) a1 += w1r[k] * xr[k];
    h1[tid] = fmaxf(a1, 0.0f);
    __syncthreads();

    float a3 = b3[tid];
    const float* w3r = w3 + tid * 64;
    #pragma unroll 4
    for (int k = 0; k < 64; ++k) a3 += w3r[k] * h1[k];
    h2[tid] = fmaxf(a3, 0.0f);
    __syncthreads();

    if (tid < 2) {
        float a2 = b2[tid];
        const float* w2r = w2 + tid * 64;
        #pragma unroll 4
        for (int k = 0; k < 64; ++k) a2 += w2r[k] * h2[k];
        out[b * 2 + tid] = a2;
    }
}

extern "C" void kernel_launch(void* const* d_in, const int* in_sizes, int n_in,
                              void* d_out, int out_size, void* d_ws, size_t ws_size,
                              hipStream_t stream) {
    const float* x    = (const float*)d_in[0];
    const float* w_ih = (const float*)d_in[1];
    const float* w_hh = (const float*)d_in[2];
    const float* b_ih = (const float*)d_in[3];
    const float* b_hh = (const float*)d_in[4];
    const float* w1   = (const float*)d_in[5];
    const float* b1   = (const float*)d_in[6];
    const float* w3   = (const float*)d_in[7];
    const float* b3   = (const float*)d_in[8];
    const float* w2   = (const float*)d_in[9];
    const float* b2   = (const float*)d_in[10];

    float* out = (float*)d_out;
    float* x7  = out + (size_t)Bv * 2;   // tuple order: (out [B,2], x7 [B,T,192])

    lstm_kernel<<<dim3((Bv / 4) * Cv), dim3(256), 0, stream>>>(x, w_ih, w_hh, b_ih, b_hh, x7);
    head_kernel<<<dim3(Bv), dim3(64), 0, stream>>>(x7, w1, b1, w3, b3, w2, b2, out);
}

// Round 4
// 456.490 us; speedup vs baseline: 1.0531x; 1.0531x over previous
//
#include <hip/hip_runtime.h>
#include <hip/hip_bf16.h>

// SeRNN forward: 6 channel-wise LSTMs (H=32) over T=256, B=1024, then MLP head.
// Outputs (concat): out [B,2] (2048 floats) then x7 [B,T,192].
//
// R2 post-mortem: VALU-bound (VALUBusy 69%, MfmaUtil 0, HBM 8%). Trans ops
// (exp/rcp at ~quarter rate) were ~1/3 of busy cycles with half of them
// redundant. This round: tanh(x)=2*sig(2x)-1 merge -> 6 trans/step instead of
// 8, no abs/copysign, no cndmask gather (only lanes<32 keep real cc/hn).

#define Bv 1024
#define Tv 256
#define Cv 6
#define Hv 32
#define Gv 128   // 4*H, PyTorch gate order i,f,g,o

#define L2E 1.442695041f   // log2(e)

// One wave per (b,c) sequence. Lane l owns gate rows l and l+64 (64 weight VGPRs).
// h state broadcast through a per-wave LDS buffer (same-address float4 reads).
__global__ __launch_bounds__(256) void lstm_kernel(
    const float* __restrict__ x,      // [B,T,C]
    const float* __restrict__ w_ih,   // [C,G]
    const float* __restrict__ w_hh,   // [C,G,H]
    const float* __restrict__ b_ih,   // [C,G]
    const float* __restrict__ b_hh,   // [C,G]
    float* __restrict__ x7)           // [B,T,C*H]
{
    __shared__ float hbuf[4][Hv];

    const int wave = threadIdx.x >> 6;
    const int lane = threadIdx.x & 63;
    const int c    = blockIdx.x % Cv;            // block-uniform channel
    const int b    = (blockIdx.x / Cv) * 4 + wave;

    // ---- load recurrent weights into registers: rows (lane) and (lane+64) ----
    float w0[Hv], w1r[Hv];
    const float* whc = w_hh + (size_t)c * (Gv * Hv);
    #pragma unroll
    for (int j4 = 0; j4 < Hv / 4; ++j4) {
        float4 a = *(const float4*)(whc + lane * Hv + j4 * 4);
        float4 q = *(const float4*)(whc + (lane + 64) * Hv + j4 * 4);
        w0[j4*4+0] = a.x; w0[j4*4+1] = a.y; w0[j4*4+2] = a.z; w0[j4*4+3] = a.w;
        w1r[j4*4+0] = q.x; w1r[j4*4+1] = q.y; w1r[j4*4+2] = q.z; w1r[j4*4+3] = q.w;
    }
    const float wi0 = w_ih[c * Gv + lane];
    const float wi1 = w_ih[c * Gv + lane + 64];
    const float bb0 = b_ih[c * Gv + lane] + b_hh[c * Gv + lane];
    const float bb1 = b_ih[c * Gv + lane + 64] + b_hh[c * Gv + lane + 64];

    // Per-lane activation constants:
    //  lanes <32: g1 is the g-gate  -> need tanh(g)  = 2*sig(2g)-1
    //  lanes>=32: g1 is the o-gate  -> need sig(o)
    const bool  lo   = (lane < 32);
    const float nsc1 = lo ? (-2.0f * L2E) : (-L2E);  // exp2(g1*nsc1) = exp(-2g)|exp(-o)
    const float fa   = lo ? 2.0f : 1.0f;             // post-fix: 2u-1 | u
    const float fb   = lo ? -1.0f : 0.0f;

    if (lane < Hv) hbuf[wave][lane] = 0.0f;   // h0 = 0 (same-wave DS ordering)
    float cc = 0.0f;                          // real cell state only in lanes<32

    const float* xp = x + (size_t)b * Tv * Cv + c;
    float* op = x7 + (size_t)b * Tv * (Cv * Hv) + c * Hv + (lane & 31);

    float xt = xp[0];
    for (int t = 0; t < Tv; ++t) {
        // software-pipeline next x_t (uniform-address scalar load)
        float xn = (t + 1 < Tv) ? xp[(size_t)(t + 1) * Cv] : 0.0f;

        // gates: two accumulator chains per gate for dep-latency cover
        float g0a = fmaf(xt, wi0, bb0), g0b = 0.0f;
        float g1a = fmaf(xt, wi1, bb1), g1b = 0.0f;
        const float4* hb4 = (const float4*)hbuf[wave];
        #pragma unroll
        for (int j4 = 0; j4 < Hv / 4; ++j4) {
            float4 h4 = hb4[j4];               // broadcast ds_read_b128
            g0a += w0[j4*4+0] * h4.x;  g1a += w1r[j4*4+0] * h4.x;
            g0b += w0[j4*4+1] * h4.y;  g1b += w1r[j4*4+1] * h4.y;
            g0a += w0[j4*4+2] * h4.z;  g1a += w1r[j4*4+2] * h4.z;
            g0b += w0[j4*4+3] * h4.w;  g1b += w1r[j4*4+3] * h4.w;
        }
        float g0 = g0a + g0b;   // lanes<32: i-gate,  lanes>=32: f-gate
        float g1 = g1a + g1b;   // lanes<32: g-gate,  lanes>=32: o-gate

        // s0 = sigmoid(g0): sig(i) | sig(f)
        float e0 = __builtin_amdgcn_exp2f(g0 * -L2E);
        float s0 = __builtin_amdgcn_rcpf(1.0f + e0);
        // to = tanh(g) | sig(o)  via one shared exp+rcp
        float e1 = __builtin_amdgcn_exp2f(g1 * nsc1);
        float u1 = __builtin_amdgcn_rcpf(1.0f + e1);
        float to = fmaf(u1, fa, fb);

        // lanes<32 gather sig(f), sig(o) from the high half; high half gets
        // garbage-but-bounded values (never read).
        float f_s = __shfl_xor(s0, 32);
        float o_s = __shfl_xor(to, 32);

        cc = fmaf(f_s, cc, s0 * to);          // lo: sig(f)*c + sig(i)*tanh(g)
        // tanh(cc) = 2*sig(2cc)-1
        float e2 = __builtin_amdgcn_exp2f(cc * (-2.0f * L2E));
        float u2 = __builtin_amdgcn_rcpf(1.0f + e2);
        float th = fmaf(u2, 2.0f, -1.0f);
        float hn = o_s * th;                  // lo: sig(o)*tanh(cc)

        if (lane < Hv) {
            hbuf[wave][lane] = hn;            // next step's broadcast source
            op[(size_t)t * (Cv * Hv)] = hn;   // x7[b,t,c*32+lane]
        }
        xt = xn;
    }
}

// MLP head on x7[:, T-1, :]: fc1(192->64)+relu, fc3(64->64)+relu, fc2(64->2)
__global__ __launch_bounds__(64) void head_kernel(
    const float* __restrict__ x7,
    const float* __restrict__ w1, const float* __restrict__ b1,
    const float* __restrict__ w3, const float* __restrict__ b3,
    const float* __restrict__ w2, const float* __restrict__ b2,
    float* __restrict__ out)
{
    const int b   = blockIdx.x;
    const int tid = threadIdx.x;
    __shared__ float xr[Cv * Hv];
    __shared__ float h1[64];
    __shared__ float h2[64];

    const float* xrow = x7 + ((size_t)b * Tv + (Tv - 1)) * (Cv * Hv);
    if (tid < 48) ((float4*)xr)[tid] = ((const float4*)xrow)[tid];
    __syncthreads();

    // fc1: 192-dot as 48 float4 terms over 4 independent accumulators
    float acc[4] = {0.f, 0.f, 0.f, 0.f};
    const float4* w4 = (const float4*)(w1 + tid * (Cv * Hv));
    const float4* x4 = (const float4*)xr;
    #pragma unroll
    for (int k = 0; k < 48; ++k) {
        float4 w = w4[k], xv = x4[k];
        acc[k & 3] += (w.x * xv.x + w.y * xv.y) + (w.z * xv.z + w.w * xv.w);
    }
    h1[tid] = fmaxf((acc[0] + acc[1]) + (acc[2] + acc[3]) + b1[tid], 0.0f);
    __syncthreads();

    // fc3: 64-dot as 16 float4 terms
    float bcc[4] = {0.f, 0.f, 0.f, 0.f};
    const float4* w34 = (const float4*)(w3 + tid * 64);
    const float4* h14 = (const float4*)h1;
    #pragma unroll
    for (int k = 0; k < 16; ++k) {
        float4 w = w34[k], hv = h14[k];
        bcc[k & 3] += (w.x * hv.x + w.y * hv.y) + (w.z * hv.z + w.w * hv.w);
    }
    h2[tid] = fmaxf((bcc[0] + bcc[1]) + (bcc[2] + bcc[3]) + b3[tid], 0.0f);
    __syncthreads();

    if (tid < 2) {
        float a2 = b2[tid];
        const float* w2r = w2 + tid * 64;
        #pragma unroll 4
        for (int k = 0; k < 64; ++k) a2 += w2r[k] * h2[k];
        out[b * 2 + tid] = a2;
    }
}

extern "C" void kernel_launch(void* const* d_in, const int* in_sizes, int n_in,
                              void* d_out, int out_size, void* d_ws, size_t ws_size,
                              hipStream_t stream) {
    const float* x    = (const float*)d_in[0];
    const float* w_ih = (const float*)d_in[1];
    const float* w_hh = (const float*)d_in[2];
    const float* b_ih = (const float*)d_in[3];
    const float* b_hh = (const float*)d_in[4];
    const float* w1   = (const float*)d_in[5];
    const float* b1   = (const float*)d_in[6];
    const float* w3   = (const float*)d_in[7];
    const float* b3   = (const float*)d_in[8];
    const float* w2   = (const float*)d_in[9];
    const float* b2   = (const float*)d_in[10];

    float* out = (float*)d_out;
    float* x7  = out + (size_t)Bv * 2;   // tuple order: (out [B,2], x7 [B,T,192])

    lstm_kernel<<<dim3((Bv / 4) * Cv), dim3(256), 0, stream>>>(x, w_ih, w_hh, b_ih, b_hh, x7);
    head_kernel<<<dim3(Bv), dim3(64), 0, stream>>>(x7, w1, b1, w3, b3, w2, b2, out);
}